// Round 1
// baseline (166.520 us; speedup 1.0000x reference)
//
#include <hip/hip_runtime.h>
#include <math.h>

// SoftVoxelOccupancyVFE: per-voxel masked mean/var of xyz + tiny MLP + sigmoid.
// N=200000 voxels, M=32 points, C=4 channels. Memory-bound (~104 MB traffic).
// Layout: 32 lanes per voxel (2 voxels/wave), lane j loads point j as float4
// -> fully coalesced. Butterfly shfl_xor reductions within 32-lane groups.

#define VOX_PER_BLOCK 8   // 256 threads / 32 lanes-per-voxel

__global__ __launch_bounds__(256) void vfe_kernel(
    const float4* __restrict__ feats,    // N*32 float4 (x,y,z,w)
    const int*    __restrict__ num_points, // N
    const float*  __restrict__ W1,       // 5x16 row-major
    const float*  __restrict__ b1,       // 16
    const float*  __restrict__ W2,       // 16x1
    const float*  __restrict__ b2,       // 1
    float*        __restrict__ out,      // N
    int N)
{
    __shared__ float sW1[80];
    __shared__ float sb1[16];
    __shared__ float sW2[16];
    __shared__ float sb2;

    const int t = threadIdx.x;
    if (t < 80) sW1[t] = W1[t];
    if (t < 16) { sb1[t] = b1[t]; sW2[t] = W2[t]; }
    if (t == 0) sb2 = b2[0];
    __syncthreads();

    const int group = t >> 5;          // 0..7
    const int lane  = t & 31;          // 0..31
    const int vox   = blockIdx.x * VOX_PER_BLOCK + group;
    if (vox >= N) return;

    const int   np        = num_points[vox];
    const float npf       = (float)np;
    const float inv_denom = 1.0f / fmaxf(npf, 1.0f);

    // coalesced: lane j reads point j (16 B) -> 512 B contiguous per group
    const float4 f = feats[(size_t)vox * 32 + lane];
    const float  m = (lane < np) ? 1.0f : 0.0f;

    // masked sum of xyz over 32 lanes (butterfly -> all lanes hold the sum)
    float sx = f.x * m, sy = f.y * m, sz = f.z * m;
    #pragma unroll
    for (int d = 16; d >= 1; d >>= 1) {
        sx += __shfl_xor(sx, d, 32);
        sy += __shfl_xor(sy, d, 32);
        sz += __shfl_xor(sz, d, 32);
    }
    const float mean_x = sx * inv_denom;
    const float mean_y = sy * inv_denom;
    const float mean_z = sz * inv_denom;

    // mean-over-channels of per-channel variance == sum(dx^2+dy^2+dz^2)/(3*denom)
    const float dx = (f.x - mean_x) * m;
    const float dy = (f.y - mean_y) * m;
    const float dz = (f.z - mean_z) * m;
    float q = dx * dx + dy * dy + dz * dz;
    #pragma unroll
    for (int d = 16; d >= 1; d >>= 1) {
        q += __shfl_xor(q, d, 32);
    }
    const float var_mean  = q * inv_denom * (1.0f / 3.0f);
    const float p_var     = expf(-0.5f * var_mean);
    const float p_density = fminf(npf, 10.0f) * 0.1f;

    // MLP: in = [p_density, p_var, mean_x, mean_y, mean_z]
    // lanes 0..15 each compute one hidden unit, then reduce over 16 lanes
    float c = 0.0f;
    if (lane < 16) {
        float h = sb1[lane]
                + p_density * sW1[lane]
                + p_var     * sW1[16 + lane]
                + mean_x    * sW1[32 + lane]
                + mean_y    * sW1[48 + lane]
                + mean_z    * sW1[64 + lane];
        h = fmaxf(h, 0.0f);
        c = h * sW2[lane];
    }
    #pragma unroll
    for (int d = 8; d >= 1; d >>= 1) {
        c += __shfl_xor(c, d, 32);   // masks 1..8 stay within 16-lane halves
    }

    if (lane == 0) {
        const float logit = c + sb2;
        out[vox] = 1.0f / (1.0f + expf(-logit));
    }
}

extern "C" void kernel_launch(void* const* d_in, const int* in_sizes, int n_in,
                              void* d_out, int out_size, void* d_ws, size_t ws_size,
                              hipStream_t stream) {
    // setup_inputs order: features, num_points, coors, W1, b1, W2, b2
    const float4* feats      = (const float4*)d_in[0];
    const int*    num_points = (const int*)d_in[1];
    // d_in[2] = coors (unused by the reference)
    const float*  W1 = (const float*)d_in[3];
    const float*  b1 = (const float*)d_in[4];
    const float*  W2 = (const float*)d_in[5];
    const float*  b2 = (const float*)d_in[6];
    float* out = (float*)d_out;

    const int N = in_sizes[1];                 // 200000
    const int blocks = (N + VOX_PER_BLOCK - 1) / VOX_PER_BLOCK;
    vfe_kernel<<<blocks, 256, 0, stream>>>(feats, num_points, W1, b1, W2, b2, out, N);
}

// Round 2
// 155.961 us; speedup vs baseline: 1.0677x; 1.0677x over previous
//
#include <hip/hip_runtime.h>
#include <math.h>

// SoftVoxelOccupancyVFE: per-voxel masked mean/var of xyz + tiny MLP + sigmoid.
// N=200000 voxels, M=32 points, C=4 channels interleaved. Memory-bound
// (~103 MB fetch floor). Layout: 8 lanes per voxel, each lane loads 4 points
// (4 independent float4 loads -> 4x memory-level parallelism vs 1), one-pass
// variance via E[x^2]-mean^2 so there is a single 3-level shuffle reduction
// phase instead of two 5-level phases.

#define LANES_PER_VOX 8
#define VOX_PER_BLOCK 32   // 256 threads / 8 lanes-per-voxel

__global__ __launch_bounds__(256) void vfe_kernel(
    const float4* __restrict__ feats,      // N*32 float4 (x,y,z,w)
    const int*    __restrict__ num_points, // N
    const float*  __restrict__ W1,         // 5x16 row-major
    const float*  __restrict__ b1,         // 16
    const float*  __restrict__ W2,         // 16x1
    const float*  __restrict__ b2,         // 1
    float*        __restrict__ out,        // N
    int N)
{
    __shared__ float sW1[80];
    __shared__ float sb1[16];
    __shared__ float sW2[16];
    __shared__ float sb2;

    const int t = threadIdx.x;
    if (t < 80) sW1[t] = W1[t];
    if (t < 16) { sb1[t] = b1[t]; sW2[t] = W2[t]; }
    if (t == 0) sb2 = b2[0];
    __syncthreads();

    const int j   = t & 7;                 // lane within voxel group
    const int vox = blockIdx.x * VOX_PER_BLOCK + (t >> 3);
    if (vox >= N) return;

    const int   np        = num_points[vox];
    const float npf       = (float)np;
    const float inv_denom = 1.0f / fmaxf(npf, 1.0f);

    // 4 independent 16 B loads per lane; wave covers 8 voxels x 512 B = 4 KB
    const float4* vbase = feats + (size_t)vox * 32;
    const float4 f0 = vbase[j];
    const float4 f1 = vbase[j + 8];
    const float4 f2 = vbase[j + 16];
    const float4 f3 = vbase[j + 24];

    const float m0 = (j      < np) ? 1.0f : 0.0f;
    const float m1 = (j + 8  < np) ? 1.0f : 0.0f;
    const float m2 = (j + 16 < np) ? 1.0f : 0.0f;
    const float m3 = (j + 24 < np) ? 1.0f : 0.0f;

    // local masked partials
    float sx = f0.x * m0 + f1.x * m1 + f2.x * m2 + f3.x * m3;
    float sy = f0.y * m0 + f1.y * m1 + f2.y * m2 + f3.y * m3;
    float sz = f0.z * m0 + f1.z * m1 + f2.z * m2 + f3.z * m3;
    float sq = m0 * (f0.x * f0.x + f0.y * f0.y + f0.z * f0.z)
             + m1 * (f1.x * f1.x + f1.y * f1.y + f1.z * f1.z)
             + m2 * (f2.x * f2.x + f2.y * f2.y + f2.z * f2.z)
             + m3 * (f3.x * f3.x + f3.y * f3.y + f3.z * f3.z);

    // single reduction phase over the 8-lane group (xor masks stay in-group)
    #pragma unroll
    for (int d = 1; d <= 4; d <<= 1) {
        sx += __shfl_xor(sx, d);
        sy += __shfl_xor(sy, d);
        sz += __shfl_xor(sz, d);
        sq += __shfl_xor(sq, d);
    }

    const float mean_x = sx * inv_denom;
    const float mean_y = sy * inv_denom;
    const float mean_z = sz * inv_denom;

    // sum m*(x-mx)^2 etc = sq - (sx^2+sy^2+sz^2)/denom  (exact for np>=1; 0 for np=0)
    float qtot = sq - (sx * sx + sy * sy + sz * sz) * inv_denom;
    float var_mean = fmaxf(qtot, 0.0f) * inv_denom * (1.0f / 3.0f);

    const float p_var     = __expf(-0.5f * var_mean);
    const float p_density = fminf(npf, 10.0f) * 0.1f;

    // MLP: lane j computes hidden units j and j+8, then 3-level reduce
    float c = 0.0f;
    #pragma unroll
    for (int u0 = 0; u0 < 16; u0 += 8) {
        const int u = u0 + j;
        float h = sb1[u]
                + p_density * sW1[u]
                + p_var     * sW1[16 + u]
                + mean_x    * sW1[32 + u]
                + mean_y    * sW1[48 + u]
                + mean_z    * sW1[64 + u];
        c += fmaxf(h, 0.0f) * sW2[u];
    }
    c += __shfl_xor(c, 1);
    c += __shfl_xor(c, 2);
    c += __shfl_xor(c, 4);

    if (j == 0) {
        const float logit = c + sb2;
        out[vox] = 1.0f / (1.0f + __expf(-logit));
    }
}

extern "C" void kernel_launch(void* const* d_in, const int* in_sizes, int n_in,
                              void* d_out, int out_size, void* d_ws, size_t ws_size,
                              hipStream_t stream) {
    // setup_inputs order: features, num_points, coors, W1, b1, W2, b2
    const float4* feats      = (const float4*)d_in[0];
    const int*    num_points = (const int*)d_in[1];
    // d_in[2] = coors (unused by the reference)
    const float*  W1 = (const float*)d_in[3];
    const float*  b1 = (const float*)d_in[4];
    const float*  W2 = (const float*)d_in[5];
    const float*  b2 = (const float*)d_in[6];
    float* out = (float*)d_out;

    const int N = in_sizes[1];                 // 200000
    const int blocks = (N + VOX_PER_BLOCK - 1) / VOX_PER_BLOCK;
    vfe_kernel<<<blocks, 256, 0, stream>>>(feats, num_points, W1, b1, W2, b2, out, N);
}

// Round 4
// 150.881 us; speedup vs baseline: 1.1037x; 1.0337x over previous
//
#include <hip/hip_runtime.h>
#include <math.h>

// SoftVoxelOccupancyVFE: per-voxel masked mean/var of xyz + tiny MLP + sigmoid.
// N=200000 voxels, M=32 points, C=4 channels interleaved. Memory-bound
// (~103 MB fetch floor ~= 16.5 us @ 6.3 TB/s).
// Layout: 4 lanes per voxel, each lane loads 8 points (8 independent float4
// loads -> high MLP), one-pass variance via E[x^2]-mean^2 -> a single 2-level
// shuffle reduction. feats loads are non-temporal (pure stream, no reuse).
// NOTE: __builtin_nontemporal_load needs a native vector type, not HIP's
// float4 struct -> use ext_vector_type(4).

typedef float floatx4 __attribute__((ext_vector_type(4)));

#define LANES_PER_VOX 4
#define VOX_PER_BLOCK 64   // 256 threads / 4 lanes-per-voxel

__global__ __launch_bounds__(256) void vfe_kernel(
    const floatx4* __restrict__ feats,     // N*32 float4 (x,y,z,w)
    const int*    __restrict__ num_points, // N
    const float*  __restrict__ W1,         // 5x16 row-major
    const float*  __restrict__ b1,         // 16
    const float*  __restrict__ W2,         // 16x1
    const float*  __restrict__ b2,         // 1
    float*        __restrict__ out,        // N
    int N)
{
    __shared__ float sW1[80];
    __shared__ float sb1[16];
    __shared__ float sW2[16];
    __shared__ float sb2;

    const int t = threadIdx.x;
    if (t < 80) sW1[t] = W1[t];
    if (t < 16) { sb1[t] = b1[t]; sW2[t] = W2[t]; }
    if (t == 0) sb2 = b2[0];
    __syncthreads();

    const int j   = t & 3;                 // lane within voxel group (0..3)
    const int vox = blockIdx.x * VOX_PER_BLOCK + (t >> 2);
    if (vox >= N) return;

    const int   np        = num_points[vox];
    const float npf       = (float)np;
    const float inv_denom = 1.0f / fmaxf(npf, 1.0f);

    // 8 independent non-temporal 16 B loads per lane; group of 4 lanes covers
    // one contiguous 64 B line per load instruction.
    const floatx4* vbase = feats + (size_t)vox * 32;
    floatx4 f[8];
    #pragma unroll
    for (int i = 0; i < 8; ++i)
        f[i] = __builtin_nontemporal_load(&vbase[j + 4 * i]);

    // local masked partials
    float sx = 0.0f, sy = 0.0f, sz = 0.0f, sq = 0.0f;
    #pragma unroll
    for (int i = 0; i < 8; ++i) {
        const float m = (j + 4 * i < np) ? 1.0f : 0.0f;
        sx += f[i].x * m;
        sy += f[i].y * m;
        sz += f[i].z * m;
        sq += m * (f[i].x * f[i].x + f[i].y * f[i].y + f[i].z * f[i].z);
    }

    // single 2-level reduction over the 4-lane group (xor masks stay in-group)
    #pragma unroll
    for (int d = 1; d <= 2; d <<= 1) {
        sx += __shfl_xor(sx, d);
        sy += __shfl_xor(sy, d);
        sz += __shfl_xor(sz, d);
        sq += __shfl_xor(sq, d);
    }

    const float mean_x = sx * inv_denom;
    const float mean_y = sy * inv_denom;
    const float mean_z = sz * inv_denom;

    // sum m*(x-mx)^2 etc = sq - (sx^2+sy^2+sz^2)/denom  (exact; 0 for np=0)
    float qtot = sq - (sx * sx + sy * sy + sz * sz) * inv_denom;
    float var_mean = fmaxf(qtot, 0.0f) * inv_denom * (1.0f / 3.0f);

    const float p_var     = __expf(-0.5f * var_mean);
    const float p_density = fminf(npf, 10.0f) * 0.1f;

    // MLP: lane j computes hidden units j, j+4, j+8, j+12; 2-level reduce
    float c = 0.0f;
    #pragma unroll
    for (int u0 = 0; u0 < 16; u0 += 4) {
        const int u = u0 + j;
        float h = sb1[u]
                + p_density * sW1[u]
                + p_var     * sW1[16 + u]
                + mean_x    * sW1[32 + u]
                + mean_y    * sW1[48 + u]
                + mean_z    * sW1[64 + u];
        c += fmaxf(h, 0.0f) * sW2[u];
    }
    c += __shfl_xor(c, 1);
    c += __shfl_xor(c, 2);

    if (j == 0) {
        const float logit = c + sb2;
        out[vox] = 1.0f / (1.0f + __expf(-logit));
    }
}

extern "C" void kernel_launch(void* const* d_in, const int* in_sizes, int n_in,
                              void* d_out, int out_size, void* d_ws, size_t ws_size,
                              hipStream_t stream) {
    // setup_inputs order: features, num_points, coors, W1, b1, W2, b2
    const floatx4* feats     = (const floatx4*)d_in[0];
    const int*    num_points = (const int*)d_in[1];
    // d_in[2] = coors (unused by the reference)
    const float*  W1 = (const float*)d_in[3];
    const float*  b1 = (const float*)d_in[4];
    const float*  W2 = (const float*)d_in[5];
    const float*  b2 = (const float*)d_in[6];
    float* out = (float*)d_out;

    const int N = in_sizes[1];                 // 200000
    const int blocks = (N + VOX_PER_BLOCK - 1) / VOX_PER_BLOCK;
    vfe_kernel<<<blocks, 256, 0, stream>>>(feats, num_points, W1, b1, W2, b2, out, N);
}